// Round 3
// baseline (394.327 us; speedup 1.0000x reference)
//
#include <hip/hip_runtime.h>
#include <math.h>

// Problem constants
#define NIMG 8
#define HDIM 128
#define WDIM 128
#define GNUM 64
#define DDIM 64
#define EDIM 32
#define UNK_CLASS 80
#define NBLK 4096                 // AE streaming blocks (exact 8-float4 cover)
#define DBLK 512                  // density blocks (dispatched FIRST)
#define TOTBLK (NBLK + DBLK)
#define AE_THREADS (NBLK*256)     // 1048576 streaming threads

typedef float floatv4 __attribute__((ext_vector_type(4)));  // native vec for nontemporal

// Single-kernel version: blocks [0,512) density-only, [512,4608) AE streaming.
// Finalization is done by the LAST block to finish (atomic ticket + device-scope
// fences) in exactly the same reduction order as the old finalize_kernel, so the
// result is bit-identical no matter which block performs it. The ticket counter
// lives at ws[TOTBLK] and is zeroed by a 4-byte hipMemsetAsync before launch
// (workspace is poisoned between iterations, so it cannot self-reset).
__global__ __launch_bounds__(256) void fused_kernel(
    const float* __restrict__ err,        // [N,256,128,128]
    const float* __restrict__ err_map,    // [N,1,128,128]
    const float* __restrict__ gt_boxes,   // [N,64,4]
    const float* __restrict__ w1,         // [1,64]
    const float* __restrict__ b1,         // [64]
    const float* __restrict__ w2,         // [64,32] row-major, row d contiguous
    const float* __restrict__ b2,         // [32]
    const float* __restrict__ w3,         // [32,1]
    const float* __restrict__ b3,         // [1]
    const int*   __restrict__ gt_classes, // [N,64]
    float* __restrict__ ws,               // [DBLK] density + [NBLK] AE partials
    unsigned* __restrict__ counter,       // ticket at ws[TOTBLK]
    float* __restrict__ out)              // [2] final losses
{
    const int t = threadIdx.x;
    const int b = blockIdx.x;

    __shared__ float4 sboxes[GNUM];
    __shared__ int    scls[GNUM];
    __shared__ float  sw1[DDIM], sb1[DDIM], sb2[EDIM], sw3[EDIM];
    __shared__ __align__(16) float sw2[DDIM*EDIM];
    __shared__ float red[4];
    __shared__ unsigned sLast;

    float part;                            // this block's partial (AE or density)

    if (b >= DBLK) {
        // ---------------- AE sum-of-squares: 8 nontemporal float4 in flight ----
        const floatv4* __restrict__ e4 = (const floatv4*)err;
        const int gtid = ((b - DBLK) << 8) | t;       // [0, 1048576)
        floatv4 v0 = __builtin_nontemporal_load(e4 + gtid + 0*AE_THREADS);
        floatv4 v1 = __builtin_nontemporal_load(e4 + gtid + 1*AE_THREADS);
        floatv4 v2 = __builtin_nontemporal_load(e4 + gtid + 2*AE_THREADS);
        floatv4 v3 = __builtin_nontemporal_load(e4 + gtid + 3*AE_THREADS);
        floatv4 v4 = __builtin_nontemporal_load(e4 + gtid + 4*AE_THREADS);
        floatv4 v5 = __builtin_nontemporal_load(e4 + gtid + 5*AE_THREADS);
        floatv4 v6 = __builtin_nontemporal_load(e4 + gtid + 6*AE_THREADS);
        floatv4 v7 = __builtin_nontemporal_load(e4 + gtid + 7*AE_THREADS);
        float s0, s1, s2, s3;
        s0 = v0.x*v0.x; s1 = v0.y*v0.y; s2 = v0.z*v0.z; s3 = v0.w*v0.w;
        s0 = fmaf(v1.x,v1.x,s0); s1 = fmaf(v1.y,v1.y,s1); s2 = fmaf(v1.z,v1.z,s2); s3 = fmaf(v1.w,v1.w,s3);
        s0 = fmaf(v2.x,v2.x,s0); s1 = fmaf(v2.y,v2.y,s1); s2 = fmaf(v2.z,v2.z,s2); s3 = fmaf(v2.w,v2.w,s3);
        s0 = fmaf(v3.x,v3.x,s0); s1 = fmaf(v3.y,v3.y,s1); s2 = fmaf(v3.z,v3.z,s2); s3 = fmaf(v3.w,v3.w,s3);
        s0 = fmaf(v4.x,v4.x,s0); s1 = fmaf(v4.y,v4.y,s1); s2 = fmaf(v4.z,v4.z,s2); s3 = fmaf(v4.w,v4.w,s3);
        s0 = fmaf(v5.x,v5.x,s0); s1 = fmaf(v5.y,v5.y,s1); s2 = fmaf(v5.z,v5.z,s2); s3 = fmaf(v5.w,v5.w,s3);
        s0 = fmaf(v6.x,v6.x,s0); s1 = fmaf(v6.y,v6.y,s1); s2 = fmaf(v6.z,v6.z,s2); s3 = fmaf(v6.w,v6.w,s3);
        s0 = fmaf(v7.x,v7.x,s0); s1 = fmaf(v7.y,v7.y,s1); s2 = fmaf(v7.z,v7.z,s2); s3 = fmaf(v7.w,v7.w,s3);
        part = (s0+s1) + (s2+s3);
    } else {
        // ---------------- density + anchor matching (pure VALU path) ----------
        const int n  = b >> 6;                 // image
        const int m  = ((b & 63) << 8) | t;    // pixel in [0,16384)

        if (t < GNUM)               sboxes[t]      = ((const float4*)gt_boxes)[n*GNUM + t];
        else if (t < 2*GNUM)        scls[t-GNUM]   = gt_classes[n*GNUM + (t-GNUM)];
        else if (t < 2*GNUM+DDIM) { sw1[t-128] = w1[t-128]; sb1[t-128] = b1[t-128]; }
        else if (t < 2*GNUM+DDIM+EDIM) { sb2[t-192] = b2[t-192]; sw3[t-192] = w3[t-192]; }
        for (int i = t; i < DDIM*EDIM; i += 256)
            sw2[i] = w2[i];                               // no transpose needed
        __syncthreads();

        // ---- anchors at this pixel (A=3 aspect ratios, detectron2 order) ----
        const float cx = (float)(m & (WDIM-1)) * 8.0f;
        const float cy = (float)(m >> 7) * 8.0f;
        const float s05 = sqrtf(0.5f), s2r = sqrtf(2.0f);
        const float hw0 = 0.5f*(32.0f/s05), hh0 = 0.5f*(32.0f*s05);
        const float hw1 = 16.0f,            hh1 = 16.0f;
        const float hw2 = 0.5f*(32.0f/s2r), hh2 = 0.5f*(32.0f*s2r);

        const float ax1[3] = {cx-hw0, cx-hw1, cx-hw2};
        const float ay1[3] = {cy-hh0, cy-hh1, cy-hh2};
        const float ax2[3] = {cx+hw0, cx+hw1, cx+hw2};
        const float ay2[3] = {cy+hh0, cy+hh1, cy+hh2};
        float areaA[3];
        #pragma unroll
        for (int a = 0; a < 3; ++a) areaA[a] = (ax2[a]-ax1[a])*(ay2[a]-ay1[a]);

        // per-anchor best GT (division-free argmax: iou = inter/dn, dn > 0)
        float bi[3] = {-1.f,-1.f,-1.f}, bd[3] = {1.f,1.f,1.f};
        int   idx[3] = {0,0,0};

        for (int g = 0; g < GNUM; ++g) {
            const float4 bx = sboxes[g];                  // LDS broadcast
            const float areaB = (bx.z-bx.x)*(bx.w-bx.y);
            #pragma unroll
            for (int a = 0; a < 3; ++a) {
                float lx = fmaxf(bx.x, ax1[a]), ly = fmaxf(bx.y, ay1[a]);
                float rx = fminf(bx.z, ax2[a]), ry = fminf(bx.w, ay2[a]);
                float iw = fmaxf(rx-lx, 0.f),   ih = fmaxf(ry-ly, 0.f);
                float inter = iw*ih;
                float dn = fmaxf(areaB + areaA[a] - inter, 1e-9f);
                // strict > keeps FIRST max, matching jnp.argmax
                if (inter*bd[a] > bi[a]*dn) { bi[a]=inter; bd[a]=dn; idx[a]=g; }
            }
        }
        const bool unk = (scls[idx[0]] == UNK_CLASS) |
                         (scls[idx[1]] == UNK_CLASS) |
                         (scls[idx[2]] == UNK_CLASS);
        const float mask = unk ? 1.0f : 0.0f;

        // ---- density MLP, loop-swapped: acc[32] over layer-2 outputs ----
        const float xv = err_map[(n << 14) + m];
        float acc[EDIM];
        #pragma unroll
        for (int e = 0; e < EDIM; ++e) acc[e] = sb2[e];

        const float4* __restrict__ sw2v = (const float4*)sw2;
        for (int d = 0; d < DDIM; ++d) {
            const float h = fmaxf(fmaf(xv, sw1[d], sb1[d]), 0.0f);
            #pragma unroll
            for (int j = 0; j < 8; ++j) {
                float4 wv = sw2v[(d << 3) + j];           // LDS broadcast (row d of w2)
                acc[4*j+0] = fmaf(h, wv.x, acc[4*j+0]);
                acc[4*j+1] = fmaf(h, wv.y, acc[4*j+1]);
                acc[4*j+2] = fmaf(h, wv.z, acc[4*j+2]);
                acc[4*j+3] = fmaf(h, wv.w, acc[4*j+3]);
            }
        }
        float p = b3[0];
        #pragma unroll
        for (int e = 0; e < EDIM; ++e)
            p = fmaf(fmaxf(acc[e], 0.0f), sw3[e], p);

        // stable BCE-with-logits term: logaddexp(0,p) - p*mask
        part = fmaxf(p, 0.0f) + log1pf(expf(-fabsf(p))) - p*mask;
    }

    // ---- block reduction ----
    float x = part;
    #pragma unroll
    for (int off = 32; off > 0; off >>= 1)
        x += __shfl_xor(x, off, 64);
    if ((t & 63) == 0) red[t >> 6] = x;
    __syncthreads();
    if (t == 0) {
        ws[b] = (red[0]+red[1]) + (red[2]+red[3]);
        // release: make ws[b] visible device-wide before taking the ticket
        __threadfence();
        unsigned old = atomicAdd(counter, 1u);   // device-scope on global mem
        sLast = (old == (unsigned)(TOTBLK - 1)) ? 1u : 0u;
    }
    __syncthreads();

    if (sLast) {
        // acquire: all 4608 partials are now visible
        __threadfence();
        // identical reduction order to the old finalize_kernel -> bit-identical out
        float sa = 0.f, sd = 0.f;
        for (int i = t; i < NBLK; i += 256) sa += ws[DBLK + i];
        for (int i = t; i < DBLK; i += 256) sd += ws[i];
        #pragma unroll
        for (int off = 32; off > 0; off >>= 1) {
            sa += __shfl_xor(sa, off, 64);
            sd += __shfl_xor(sd, off, 64);
        }
        if ((t & 63) == 0) { red[t >> 6] = sa; sw1[t >> 6] = sd; }  // reuse LDS
        __syncthreads();
        if (t == 0) {
            out[0] = ((red[0]+red[1])+(red[2]+red[3])) * (1.0f/33554432.0f); // loss_ae
            out[1] = ((sw1[0]+sw1[1])+(sw1[2]+sw1[3])) * (1.0f/131072.0f);   // loss_density
        }
    }
}

extern "C" void kernel_launch(void* const* d_in, const int* in_sizes, int n_in,
                              void* d_out, int out_size, void* d_ws, size_t ws_size,
                              hipStream_t stream) {
    const float* err        = (const float*)d_in[0];
    const float* err_map    = (const float*)d_in[1];
    const float* gt_boxes   = (const float*)d_in[2];
    const float* w1         = (const float*)d_in[3];
    const float* b1         = (const float*)d_in[4];
    const float* w2         = (const float*)d_in[5];
    const float* b2         = (const float*)d_in[6];
    const float* w3         = (const float*)d_in[7];
    const float* b3         = (const float*)d_in[8];
    const int*   gt_classes = (const int*)d_in[9];
    float* out = (float*)d_out;
    float* ws  = (float*)d_ws;
    unsigned* counter = (unsigned*)(ws + TOTBLK);

    // workspace is poisoned between iterations -> zero the 4-byte ticket
    (void)hipMemsetAsync(counter, 0, sizeof(unsigned), stream);
    fused_kernel<<<TOTBLK, 256, 0, stream>>>(err, err_map, gt_boxes, w1, b1, w2, b2,
                                             w3, b3, gt_classes, ws, counter, out);
}

// Round 4
// 213.376 us; speedup vs baseline: 1.8480x; 1.8480x over previous
//
#include <hip/hip_runtime.h>
#include <math.h>

// Problem constants
#define NIMG 8
#define HDIM 128
#define WDIM 128
#define GNUM 64
#define DDIM 64
#define EDIM 32
#define UNK_CLASS 80
#define NBLK 4096                 // AE streaming blocks (exact 8-float4 cover)
#define DBLK 512                  // logical density partial count (ws layout unchanged)
#define DGRID 256                 // physical density blocks; each covers 2 logical blocks
#define TOTBLK (DGRID + NBLK)
#define AE_THREADS (NBLK*256)     // 1048576 streaming threads

// Reverted R3's nontemporal loads and fence/ticket (the per-block __threadfence
// destroyed streaming BW: 290 GB/s, kernel 232us). Back to the two-kernel
// structure, with ONE change vs R1: each density lane now processes TWO pixels
// (old logical blocks 2b and 2b+1), so the 512 ds_read_b128 broadcasts of w2
// per wave are amortized over 2x the pixels -> density LDS-pipe time halves.
// Bit-exactness: each logical block keeps the same lane<->pixel assignment,
// identical per-lane arithmetic, identical 64-lane butterfly, and writes the
// same ws slot, so the final reduction consumes bitwise-identical partials.
__global__ __launch_bounds__(256) void fused_kernel(
    const float* __restrict__ err,        // [N,256,128,128]
    const float* __restrict__ err_map,    // [N,1,128,128]
    const float* __restrict__ gt_boxes,   // [N,64,4]
    const float* __restrict__ w1,         // [1,64]
    const float* __restrict__ b1,         // [64]
    const float* __restrict__ w2,         // [64,32] row-major, row d contiguous
    const float* __restrict__ b2,         // [32]
    const float* __restrict__ w3,         // [32,1]
    const float* __restrict__ b3,         // [1]
    const int*   __restrict__ gt_classes, // [N,64]
    float* __restrict__ ws)               // [DBLK] density partials + [NBLK] AE partials
{
    const int t = threadIdx.x;
    const int b = blockIdx.x;

    __shared__ float4 sboxes[GNUM];
    __shared__ int    scls[GNUM];
    __shared__ float  sw1[DDIM], sb1[DDIM], sb2[EDIM], sw3[EDIM];
    __shared__ __align__(16) float sw2[DDIM*EDIM];
    __shared__ float redA[4], redB[4];

    if (b >= DGRID) {
        // ---------------- AE sum-of-squares: 8 float4 in flight ----------------
        const float4* __restrict__ e4 = (const float4*)err;
        const int gtid = ((b - DGRID) << 8) | t;      // [0, 1048576)
        float4 v0 = e4[gtid + 0*AE_THREADS];
        float4 v1 = e4[gtid + 1*AE_THREADS];
        float4 v2 = e4[gtid + 2*AE_THREADS];
        float4 v3 = e4[gtid + 3*AE_THREADS];
        float4 v4 = e4[gtid + 4*AE_THREADS];
        float4 v5 = e4[gtid + 5*AE_THREADS];
        float4 v6 = e4[gtid + 6*AE_THREADS];
        float4 v7 = e4[gtid + 7*AE_THREADS];
        float s0, s1, s2, s3;
        s0 = v0.x*v0.x; s1 = v0.y*v0.y; s2 = v0.z*v0.z; s3 = v0.w*v0.w;
        s0 = fmaf(v1.x,v1.x,s0); s1 = fmaf(v1.y,v1.y,s1); s2 = fmaf(v1.z,v1.z,s2); s3 = fmaf(v1.w,v1.w,s3);
        s0 = fmaf(v2.x,v2.x,s0); s1 = fmaf(v2.y,v2.y,s1); s2 = fmaf(v2.z,v2.z,s2); s3 = fmaf(v2.w,v2.w,s3);
        s0 = fmaf(v3.x,v3.x,s0); s1 = fmaf(v3.y,v3.y,s1); s2 = fmaf(v3.z,v3.z,s2); s3 = fmaf(v3.w,v3.w,s3);
        s0 = fmaf(v4.x,v4.x,s0); s1 = fmaf(v4.y,v4.y,s1); s2 = fmaf(v4.z,v4.z,s2); s3 = fmaf(v4.w,v4.w,s3);
        s0 = fmaf(v5.x,v5.x,s0); s1 = fmaf(v5.y,v5.y,s1); s2 = fmaf(v5.z,v5.z,s2); s3 = fmaf(v5.w,v5.w,s3);
        s0 = fmaf(v6.x,v6.x,s0); s1 = fmaf(v6.y,v6.y,s1); s2 = fmaf(v6.z,v6.z,s2); s3 = fmaf(v6.w,v6.w,s3);
        s0 = fmaf(v7.x,v7.x,s0); s1 = fmaf(v7.y,v7.y,s1); s2 = fmaf(v7.z,v7.z,s2); s3 = fmaf(v7.w,v7.w,s3);
        float x = (s0+s1) + (s2+s3);
        #pragma unroll
        for (int off = 32; off > 0; off >>= 1)
            x += __shfl_xor(x, off, 64);
        if ((t & 63) == 0) redA[t >> 6] = x;
        __syncthreads();
        if (t == 0)
            ws[DBLK + (b - DGRID)] = (redA[0]+redA[1]) + (redA[2]+redA[3]);
    } else {
        // ------- density + anchor matching: 2 pixels/lane (logical 2b, 2b+1) ----
        const int n  = b >> 5;                       // image = (2b)>>6
        const int m0 = ((2*b & 63) << 8) | t;        // pixel of logical block 2b
        const int m1 = m0 + 256;                     // pixel of logical block 2b+1

        if (t < GNUM)               sboxes[t]      = ((const float4*)gt_boxes)[n*GNUM + t];
        else if (t < 2*GNUM)        scls[t-GNUM]   = gt_classes[n*GNUM + (t-GNUM)];
        else if (t < 2*GNUM+DDIM) { sw1[t-128] = w1[t-128]; sb1[t-128] = b1[t-128]; }
        else if (t < 2*GNUM+DDIM+EDIM) { sb2[t-192] = b2[t-192]; sw3[t-192] = w3[t-192]; }
        for (int i = t; i < DDIM*EDIM; i += 256)
            sw2[i] = w2[i];                          // no transpose needed
        __syncthreads();

        // ---- anchors: x-geometry identical for both pixels (same column) ----
        const float cx  = (float)(m0 & (WDIM-1)) * 8.0f;
        const float cy0 = (float)(m0 >> 7) * 8.0f;
        const float cy1 = (float)(m1 >> 7) * 8.0f;
        const float s05 = sqrtf(0.5f), s2r = sqrtf(2.0f);
        const float hw0 = 0.5f*(32.0f/s05), hh0 = 0.5f*(32.0f*s05);
        const float hw1 = 16.0f,            hh1 = 16.0f;
        const float hw2 = 0.5f*(32.0f/s2r), hh2 = 0.5f*(32.0f*s2r);

        const float ax1[3] = {cx-hw0, cx-hw1, cx-hw2};
        const float ax2[3] = {cx+hw0, cx+hw1, cx+hw2};
        const float ay1a[3] = {cy0-hh0, cy0-hh1, cy0-hh2};
        const float ay2a[3] = {cy0+hh0, cy0+hh1, cy0+hh2};
        const float ay1b[3] = {cy1-hh0, cy1-hh1, cy1-hh2};
        const float ay2b[3] = {cy1+hh0, cy1+hh1, cy1+hh2};
        float areaA[3];
        #pragma unroll
        for (int a = 0; a < 3; ++a) areaA[a] = (ax2[a]-ax1[a])*(2.0f*hh0*(a==0)+2.0f*hh1*(a==1)+2.0f*hh2*(a==2));
        // (width*height; height is pixel-independent, written explicitly below
        //  to keep the EXACT original expression form per anchor)
        areaA[0] = (ax2[0]-ax1[0])*(ay2a[0]-ay1a[0]);
        areaA[1] = (ax2[1]-ax1[1])*(ay2a[1]-ay1a[1]);
        areaA[2] = (ax2[2]-ax1[2])*(ay2a[2]-ay1a[2]);

        // per-anchor best GT for both pixels (division-free argmax)
        float biA[3] = {-1.f,-1.f,-1.f}, bdA[3] = {1.f,1.f,1.f};
        float biB[3] = {-1.f,-1.f,-1.f}, bdB[3] = {1.f,1.f,1.f};
        int   idxA[3] = {0,0,0}, idxB[3] = {0,0,0};

        for (int g = 0; g < GNUM; ++g) {
            const float4 bx = sboxes[g];              // LDS broadcast
            const float areaB = (bx.z-bx.x)*(bx.w-bx.y);
            #pragma unroll
            for (int a = 0; a < 3; ++a) {
                // x-part shared between the two pixels (identical inputs)
                float lx = fmaxf(bx.x, ax1[a]);
                float rx = fminf(bx.z, ax2[a]);
                float iw = fmaxf(rx-lx, 0.f);
                // pixel 0
                {
                    float ly = fmaxf(bx.y, ay1a[a]), ry = fminf(bx.w, ay2a[a]);
                    float ih = fmaxf(ry-ly, 0.f);
                    float inter = iw*ih;
                    float dn = fmaxf(areaB + areaA[a] - inter, 1e-9f);
                    if (inter*bdA[a] > biA[a]*dn) { biA[a]=inter; bdA[a]=dn; idxA[a]=g; }
                }
                // pixel 1
                {
                    float ly = fmaxf(bx.y, ay1b[a]), ry = fminf(bx.w, ay2b[a]);
                    float ih = fmaxf(ry-ly, 0.f);
                    float inter = iw*ih;
                    float dn = fmaxf(areaB + areaA[a] - inter, 1e-9f);
                    if (inter*bdB[a] > biB[a]*dn) { biB[a]=inter; bdB[a]=dn; idxB[a]=g; }
                }
            }
        }
        const float maskA = ((scls[idxA[0]] == UNK_CLASS) |
                             (scls[idxA[1]] == UNK_CLASS) |
                             (scls[idxA[2]] == UNK_CLASS)) ? 1.0f : 0.0f;
        const float maskB = ((scls[idxB[0]] == UNK_CLASS) |
                             (scls[idxB[1]] == UNK_CLASS) |
                             (scls[idxB[2]] == UNK_CLASS)) ? 1.0f : 0.0f;

        // ---- density MLP for both pixels; w2 row read ONCE per d ----
        const float xv0 = err_map[(n << 14) + m0];
        const float xv1 = err_map[(n << 14) + m1];
        float acc0[EDIM], acc1[EDIM];
        #pragma unroll
        for (int e = 0; e < EDIM; ++e) { acc0[e] = sb2[e]; acc1[e] = sb2[e]; }

        const float4* __restrict__ sw2v = (const float4*)sw2;
        for (int d = 0; d < DDIM; ++d) {
            const float h0 = fmaxf(fmaf(xv0, sw1[d], sb1[d]), 0.0f);
            const float h1 = fmaxf(fmaf(xv1, sw1[d], sb1[d]), 0.0f);
            #pragma unroll
            for (int j = 0; j < 8; ++j) {
                float4 wv = sw2v[(d << 3) + j];       // LDS broadcast, shared by both
                acc0[4*j+0] = fmaf(h0, wv.x, acc0[4*j+0]);
                acc0[4*j+1] = fmaf(h0, wv.y, acc0[4*j+1]);
                acc0[4*j+2] = fmaf(h0, wv.z, acc0[4*j+2]);
                acc0[4*j+3] = fmaf(h0, wv.w, acc0[4*j+3]);
                acc1[4*j+0] = fmaf(h1, wv.x, acc1[4*j+0]);
                acc1[4*j+1] = fmaf(h1, wv.y, acc1[4*j+1]);
                acc1[4*j+2] = fmaf(h1, wv.z, acc1[4*j+2]);
                acc1[4*j+3] = fmaf(h1, wv.w, acc1[4*j+3]);
            }
        }
        float p0 = b3[0], p1 = b3[0];
        #pragma unroll
        for (int e = 0; e < EDIM; ++e) {
            p0 = fmaf(fmaxf(acc0[e], 0.0f), sw3[e], p0);
            p1 = fmaf(fmaxf(acc1[e], 0.0f), sw3[e], p1);
        }

        // stable BCE-with-logits terms
        float x0 = fmaxf(p0, 0.0f) + log1pf(expf(-fabsf(p0))) - p0*maskA;
        float x1 = fmaxf(p1, 0.0f) + log1pf(expf(-fabsf(p1))) - p1*maskB;

        // two independent butterflies (same shuffle order as the 1-pixel kernel)
        #pragma unroll
        for (int off = 32; off > 0; off >>= 1) {
            x0 += __shfl_xor(x0, off, 64);
            x1 += __shfl_xor(x1, off, 64);
        }
        if ((t & 63) == 0) { redA[t >> 6] = x0; redB[t >> 6] = x1; }
        __syncthreads();
        if (t == 0) {
            ws[2*b]   = (redA[0]+redA[1]) + (redA[2]+redA[3]);   // logical block 2b
            ws[2*b+1] = (redB[0]+redB[1]) + (redB[2]+redB[3]);   // logical block 2b+1
        }
    }
}

__global__ __launch_bounds__(256) void finalize_kernel(const float* __restrict__ ws,
                                                       float* __restrict__ out)
{
    const int t = threadIdx.x;
    float sa = 0.f, sd = 0.f;
    for (int i = t; i < NBLK; i += 256) sa += ws[DBLK + i];
    for (int i = t; i < DBLK; i += 256) sd += ws[i];
    #pragma unroll
    for (int off = 32; off > 0; off >>= 1) {
        sa += __shfl_xor(sa, off, 64);
        sd += __shfl_xor(sd, off, 64);
    }
    __shared__ float ra[4], rd[4];
    if ((t & 63) == 0) { ra[t >> 6] = sa; rd[t >> 6] = sd; }
    __syncthreads();
    if (t == 0) {
        out[0] = ((ra[0]+ra[1])+(ra[2]+ra[3])) * (1.0f/33554432.0f); // loss_ae
        out[1] = ((rd[0]+rd[1])+(rd[2]+rd[3])) * (1.0f/131072.0f);   // loss_density
    }
}

extern "C" void kernel_launch(void* const* d_in, const int* in_sizes, int n_in,
                              void* d_out, int out_size, void* d_ws, size_t ws_size,
                              hipStream_t stream) {
    const float* err        = (const float*)d_in[0];
    const float* err_map    = (const float*)d_in[1];
    const float* gt_boxes   = (const float*)d_in[2];
    const float* w1         = (const float*)d_in[3];
    const float* b1         = (const float*)d_in[4];
    const float* w2         = (const float*)d_in[5];
    const float* b2         = (const float*)d_in[6];
    const float* w3         = (const float*)d_in[7];
    const float* b3         = (const float*)d_in[8];
    const int*   gt_classes = (const int*)d_in[9];
    float* out = (float*)d_out;
    float* ws  = (float*)d_ws;

    fused_kernel<<<TOTBLK, 256, 0, stream>>>(err, err_map, gt_boxes, w1, b1, w2, b2,
                                             w3, b3, gt_classes, ws);
    finalize_kernel<<<1, 256, 0, stream>>>(ws, out);
}

// Round 5
// 213.373 us; speedup vs baseline: 1.8481x; 1.0000x over previous
//
#include <hip/hip_runtime.h>
#include <math.h>

// Problem constants
#define NIMG 8
#define HDIM 128
#define WDIM 128
#define GNUM 64
#define DDIM 64
#define EDIM 32
#define UNK_CLASS 80
#define NBLK 4096                 // logical AE partial count (ws layout unchanged)
#define DBLK 512                  // logical density partial count (ws layout unchanged)
#define DGRID 256                 // physical density blocks (2 pixels/lane, as R4)
#define AEGRID 1024               // physical AE blocks; each covers 4 logical blocks
#define AESUB 4
#define TOTBLK (DGRID + AEGRID)   // 1280 blocks ~= 5/CU -> fully co-resident grid
#define AE_THREADS (NBLK*256)     // 1048576 logical streaming threads

// R5: co-resident AE grid. R3<->R4 arithmetic shows fused_kernel ~52us at only
// ~2.6 TB/s (vs ~6.3 achievable, and ~50% of err is L3-resident per R3's
// FETCH_SIZE=66MB) -> not BW-bound; suspected block-turnover/launch latency of
// 4608 ~1us blocks. Now 1024 AE blocks each produce FOUR logical partials
// (16 loads in flight in 2 pair-batches, one barrier), grid fits on-chip.
// Bit-exactness: every logical block keeps its exact 8-load tree, butterfly
// order, and ws slot; density path identical to R4; finalize identical.
__global__ __launch_bounds__(256) void fused_kernel(
    const float* __restrict__ err,        // [N,256,128,128]
    const float* __restrict__ err_map,    // [N,1,128,128]
    const float* __restrict__ gt_boxes,   // [N,64,4]
    const float* __restrict__ w1,         // [1,64]
    const float* __restrict__ b1,         // [64]
    const float* __restrict__ w2,         // [64,32] row-major, row d contiguous
    const float* __restrict__ b2,         // [32]
    const float* __restrict__ w3,         // [32,1]
    const float* __restrict__ b3,         // [1]
    const int*   __restrict__ gt_classes, // [N,64]
    float* __restrict__ ws)               // [DBLK] density partials + [NBLK] AE partials
{
    const int t = threadIdx.x;
    const int b = blockIdx.x;

    __shared__ float4 sboxes[GNUM];
    __shared__ int    scls[GNUM];
    __shared__ float  sw1[DDIM], sb1[DDIM], sb2[EDIM], sw3[EDIM];
    __shared__ __align__(16) float sw2[DDIM*EDIM];
    __shared__ float redS[AESUB][4];      // AE: 4 sub-block reductions; density uses [0],[1]

    if (b >= DGRID) {
        // ------------- AE sum-of-squares: 4 logical blocks per block ----------
        const float4* __restrict__ e4 = (const float4*)err;
        const int j0 = (b - DGRID) * AESUB;           // first logical block
        float part[AESUB];

        // pair-batched: 16 loads in flight, then two exact 8-load trees
        #define AE_PAIR(JA, JB, PA, PB) do {                                   \
            const int gA = ((JA) << 8) | t;                                    \
            const int gB = ((JB) << 8) | t;                                    \
            float4 a0 = e4[gA + 0*AE_THREADS], b0 = e4[gB + 0*AE_THREADS];     \
            float4 a1 = e4[gA + 1*AE_THREADS], b1v = e4[gB + 1*AE_THREADS];    \
            float4 a2 = e4[gA + 2*AE_THREADS], b2v = e4[gB + 2*AE_THREADS];    \
            float4 a3 = e4[gA + 3*AE_THREADS], b3v = e4[gB + 3*AE_THREADS];    \
            float4 a4 = e4[gA + 4*AE_THREADS], b4 = e4[gB + 4*AE_THREADS];     \
            float4 a5 = e4[gA + 5*AE_THREADS], b5 = e4[gB + 5*AE_THREADS];     \
            float4 a6 = e4[gA + 6*AE_THREADS], b6 = e4[gB + 6*AE_THREADS];     \
            float4 a7 = e4[gA + 7*AE_THREADS], b7 = e4[gB + 7*AE_THREADS];     \
            float s0, s1, s2, s3;                                              \
            s0 = a0.x*a0.x; s1 = a0.y*a0.y; s2 = a0.z*a0.z; s3 = a0.w*a0.w;    \
            s0 = fmaf(a1.x,a1.x,s0); s1 = fmaf(a1.y,a1.y,s1); s2 = fmaf(a1.z,a1.z,s2); s3 = fmaf(a1.w,a1.w,s3); \
            s0 = fmaf(a2.x,a2.x,s0); s1 = fmaf(a2.y,a2.y,s1); s2 = fmaf(a2.z,a2.z,s2); s3 = fmaf(a2.w,a2.w,s3); \
            s0 = fmaf(a3.x,a3.x,s0); s1 = fmaf(a3.y,a3.y,s1); s2 = fmaf(a3.z,a3.z,s2); s3 = fmaf(a3.w,a3.w,s3); \
            s0 = fmaf(a4.x,a4.x,s0); s1 = fmaf(a4.y,a4.y,s1); s2 = fmaf(a4.z,a4.z,s2); s3 = fmaf(a4.w,a4.w,s3); \
            s0 = fmaf(a5.x,a5.x,s0); s1 = fmaf(a5.y,a5.y,s1); s2 = fmaf(a5.z,a5.z,s2); s3 = fmaf(a5.w,a5.w,s3); \
            s0 = fmaf(a6.x,a6.x,s0); s1 = fmaf(a6.y,a6.y,s1); s2 = fmaf(a6.z,a6.z,s2); s3 = fmaf(a6.w,a6.w,s3); \
            s0 = fmaf(a7.x,a7.x,s0); s1 = fmaf(a7.y,a7.y,s1); s2 = fmaf(a7.z,a7.z,s2); s3 = fmaf(a7.w,a7.w,s3); \
            (PA) = (s0+s1) + (s2+s3);                                          \
            s0 = b0.x*b0.x; s1 = b0.y*b0.y; s2 = b0.z*b0.z; s3 = b0.w*b0.w;    \
            s0 = fmaf(b1v.x,b1v.x,s0); s1 = fmaf(b1v.y,b1v.y,s1); s2 = fmaf(b1v.z,b1v.z,s2); s3 = fmaf(b1v.w,b1v.w,s3); \
            s0 = fmaf(b2v.x,b2v.x,s0); s1 = fmaf(b2v.y,b2v.y,s1); s2 = fmaf(b2v.z,b2v.z,s2); s3 = fmaf(b2v.w,b2v.w,s3); \
            s0 = fmaf(b3v.x,b3v.x,s0); s1 = fmaf(b3v.y,b3v.y,s1); s2 = fmaf(b3v.z,b3v.z,s2); s3 = fmaf(b3v.w,b3v.w,s3); \
            s0 = fmaf(b4.x,b4.x,s0); s1 = fmaf(b4.y,b4.y,s1); s2 = fmaf(b4.z,b4.z,s2); s3 = fmaf(b4.w,b4.w,s3); \
            s0 = fmaf(b5.x,b5.x,s0); s1 = fmaf(b5.y,b5.y,s1); s2 = fmaf(b5.z,b5.z,s2); s3 = fmaf(b5.w,b5.w,s3); \
            s0 = fmaf(b6.x,b6.x,s0); s1 = fmaf(b6.y,b6.y,s1); s2 = fmaf(b6.z,b6.z,s2); s3 = fmaf(b6.w,b6.w,s3); \
            s0 = fmaf(b7.x,b7.x,s0); s1 = fmaf(b7.y,b7.y,s1); s2 = fmaf(b7.z,b7.z,s2); s3 = fmaf(b7.w,b7.w,s3); \
            (PB) = (s0+s1) + (s2+s3);                                          \
        } while (0)

        AE_PAIR(j0+0, j0+1, part[0], part[1]);
        AE_PAIR(j0+2, j0+3, part[2], part[3]);
        #undef AE_PAIR

        // four independent butterflies, identical shuffle order per logical block
        #pragma unroll
        for (int s = 0; s < AESUB; ++s) {
            float x = part[s];
            #pragma unroll
            for (int off = 32; off > 0; off >>= 1)
                x += __shfl_xor(x, off, 64);
            if ((t & 63) == 0) redS[s][t >> 6] = x;
        }
        __syncthreads();
        if (t < AESUB)   // lanes 0..3 each store one logical partial
            ws[DBLK + j0 + t] = (redS[t][0]+redS[t][1]) + (redS[t][2]+redS[t][3]);
    } else {
        // ------- density + anchor matching: 2 pixels/lane (logical 2b, 2b+1) ----
        const int n  = b >> 5;                       // image = (2b)>>6
        const int m0 = ((2*b & 63) << 8) | t;        // pixel of logical block 2b
        const int m1 = m0 + 256;                     // pixel of logical block 2b+1

        if (t < GNUM)               sboxes[t]      = ((const float4*)gt_boxes)[n*GNUM + t];
        else if (t < 2*GNUM)        scls[t-GNUM]   = gt_classes[n*GNUM + (t-GNUM)];
        else if (t < 2*GNUM+DDIM) { sw1[t-128] = w1[t-128]; sb1[t-128] = b1[t-128]; }
        else if (t < 2*GNUM+DDIM+EDIM) { sb2[t-192] = b2[t-192]; sw3[t-192] = w3[t-192]; }
        for (int i = t; i < DDIM*EDIM; i += 256)
            sw2[i] = w2[i];                          // no transpose needed
        __syncthreads();

        // ---- anchors: x-geometry identical for both pixels (same column) ----
        const float cx  = (float)(m0 & (WDIM-1)) * 8.0f;
        const float cy0 = (float)(m0 >> 7) * 8.0f;
        const float cy1 = (float)(m1 >> 7) * 8.0f;
        const float s05 = sqrtf(0.5f), s2r = sqrtf(2.0f);
        const float hw0 = 0.5f*(32.0f/s05), hh0 = 0.5f*(32.0f*s05);
        const float hw1 = 16.0f,            hh1 = 16.0f;
        const float hw2 = 0.5f*(32.0f/s2r), hh2 = 0.5f*(32.0f*s2r);

        const float ax1[3] = {cx-hw0, cx-hw1, cx-hw2};
        const float ax2[3] = {cx+hw0, cx+hw1, cx+hw2};
        const float ay1a[3] = {cy0-hh0, cy0-hh1, cy0-hh2};
        const float ay2a[3] = {cy0+hh0, cy0+hh1, cy0+hh2};
        const float ay1b[3] = {cy1-hh0, cy1-hh1, cy1-hh2};
        const float ay2b[3] = {cy1+hh0, cy1+hh1, cy1+hh2};
        float areaA[3];
        areaA[0] = (ax2[0]-ax1[0])*(ay2a[0]-ay1a[0]);
        areaA[1] = (ax2[1]-ax1[1])*(ay2a[1]-ay1a[1]);
        areaA[2] = (ax2[2]-ax1[2])*(ay2a[2]-ay1a[2]);

        // per-anchor best GT for both pixels (division-free argmax)
        float biA[3] = {-1.f,-1.f,-1.f}, bdA[3] = {1.f,1.f,1.f};
        float biB[3] = {-1.f,-1.f,-1.f}, bdB[3] = {1.f,1.f,1.f};
        int   idxA[3] = {0,0,0}, idxB[3] = {0,0,0};

        for (int g = 0; g < GNUM; ++g) {
            const float4 bx = sboxes[g];              // LDS broadcast
            const float areaB = (bx.z-bx.x)*(bx.w-bx.y);
            #pragma unroll
            for (int a = 0; a < 3; ++a) {
                float lx = fmaxf(bx.x, ax1[a]);
                float rx = fminf(bx.z, ax2[a]);
                float iw = fmaxf(rx-lx, 0.f);
                {
                    float ly = fmaxf(bx.y, ay1a[a]), ry = fminf(bx.w, ay2a[a]);
                    float ih = fmaxf(ry-ly, 0.f);
                    float inter = iw*ih;
                    float dn = fmaxf(areaB + areaA[a] - inter, 1e-9f);
                    if (inter*bdA[a] > biA[a]*dn) { biA[a]=inter; bdA[a]=dn; idxA[a]=g; }
                }
                {
                    float ly = fmaxf(bx.y, ay1b[a]), ry = fminf(bx.w, ay2b[a]);
                    float ih = fmaxf(ry-ly, 0.f);
                    float inter = iw*ih;
                    float dn = fmaxf(areaB + areaA[a] - inter, 1e-9f);
                    if (inter*bdB[a] > biB[a]*dn) { biB[a]=inter; bdB[a]=dn; idxB[a]=g; }
                }
            }
        }
        const float maskA = ((scls[idxA[0]] == UNK_CLASS) |
                             (scls[idxA[1]] == UNK_CLASS) |
                             (scls[idxA[2]] == UNK_CLASS)) ? 1.0f : 0.0f;
        const float maskB = ((scls[idxB[0]] == UNK_CLASS) |
                             (scls[idxB[1]] == UNK_CLASS) |
                             (scls[idxB[2]] == UNK_CLASS)) ? 1.0f : 0.0f;

        // ---- density MLP for both pixels; w2 row read ONCE per d ----
        const float xv0 = err_map[(n << 14) + m0];
        const float xv1 = err_map[(n << 14) + m1];
        float acc0[EDIM], acc1[EDIM];
        #pragma unroll
        for (int e = 0; e < EDIM; ++e) { acc0[e] = sb2[e]; acc1[e] = sb2[e]; }

        const float4* __restrict__ sw2v = (const float4*)sw2;
        for (int d = 0; d < DDIM; ++d) {
            const float h0 = fmaxf(fmaf(xv0, sw1[d], sb1[d]), 0.0f);
            const float h1 = fmaxf(fmaf(xv1, sw1[d], sb1[d]), 0.0f);
            #pragma unroll
            for (int j = 0; j < 8; ++j) {
                float4 wv = sw2v[(d << 3) + j];       // LDS broadcast, shared by both
                acc0[4*j+0] = fmaf(h0, wv.x, acc0[4*j+0]);
                acc0[4*j+1] = fmaf(h0, wv.y, acc0[4*j+1]);
                acc0[4*j+2] = fmaf(h0, wv.z, acc0[4*j+2]);
                acc0[4*j+3] = fmaf(h0, wv.w, acc0[4*j+3]);
                acc1[4*j+0] = fmaf(h1, wv.x, acc1[4*j+0]);
                acc1[4*j+1] = fmaf(h1, wv.y, acc1[4*j+1]);
                acc1[4*j+2] = fmaf(h1, wv.z, acc1[4*j+2]);
                acc1[4*j+3] = fmaf(h1, wv.w, acc1[4*j+3]);
            }
        }
        float p0 = b3[0], p1 = b3[0];
        #pragma unroll
        for (int e = 0; e < EDIM; ++e) {
            p0 = fmaf(fmaxf(acc0[e], 0.0f), sw3[e], p0);
            p1 = fmaf(fmaxf(acc1[e], 0.0f), sw3[e], p1);
        }

        // stable BCE-with-logits terms
        float x0 = fmaxf(p0, 0.0f) + log1pf(expf(-fabsf(p0))) - p0*maskA;
        float x1 = fmaxf(p1, 0.0f) + log1pf(expf(-fabsf(p1))) - p1*maskB;

        #pragma unroll
        for (int off = 32; off > 0; off >>= 1) {
            x0 += __shfl_xor(x0, off, 64);
            x1 += __shfl_xor(x1, off, 64);
        }
        if ((t & 63) == 0) { redS[0][t >> 6] = x0; redS[1][t >> 6] = x1; }
        __syncthreads();
        if (t == 0) {
            ws[2*b]   = (redS[0][0]+redS[0][1]) + (redS[0][2]+redS[0][3]);   // logical 2b
            ws[2*b+1] = (redS[1][0]+redS[1][1]) + (redS[1][2]+redS[1][3]);   // logical 2b+1
        }
    }
}

__global__ __launch_bounds__(256) void finalize_kernel(const float* __restrict__ ws,
                                                       float* __restrict__ out)
{
    const int t = threadIdx.x;
    float sa = 0.f, sd = 0.f;
    for (int i = t; i < NBLK; i += 256) sa += ws[DBLK + i];
    for (int i = t; i < DBLK; i += 256) sd += ws[i];
    #pragma unroll
    for (int off = 32; off > 0; off >>= 1) {
        sa += __shfl_xor(sa, off, 64);
        sd += __shfl_xor(sd, off, 64);
    }
    __shared__ float ra[4], rd[4];
    if ((t & 63) == 0) { ra[t >> 6] = sa; rd[t >> 6] = sd; }
    __syncthreads();
    if (t == 0) {
        out[0] = ((ra[0]+ra[1])+(ra[2]+ra[3])) * (1.0f/33554432.0f); // loss_ae
        out[1] = ((rd[0]+rd[1])+(rd[2]+rd[3])) * (1.0f/131072.0f);   // loss_density
    }
}

extern "C" void kernel_launch(void* const* d_in, const int* in_sizes, int n_in,
                              void* d_out, int out_size, void* d_ws, size_t ws_size,
                              hipStream_t stream) {
    const float* err        = (const float*)d_in[0];
    const float* err_map    = (const float*)d_in[1];
    const float* gt_boxes   = (const float*)d_in[2];
    const float* w1         = (const float*)d_in[3];
    const float* b1         = (const float*)d_in[4];
    const float* w2         = (const float*)d_in[5];
    const float* b2         = (const float*)d_in[6];
    const float* w3         = (const float*)d_in[7];
    const float* b3         = (const float*)d_in[8];
    const int*   gt_classes = (const int*)d_in[9];
    float* out = (float*)d_out;
    float* ws  = (float*)d_ws;

    fused_kernel<<<TOTBLK, 256, 0, stream>>>(err, err_map, gt_boxes, w1, b1, w2, b2,
                                             w3, b3, gt_classes, ws);
    finalize_kernel<<<1, 256, 0, stream>>>(ws, out);
}

// Round 6
// 207.592 us; speedup vs baseline: 1.8995x; 1.0278x over previous
//
#include <hip/hip_runtime.h>
#include <math.h>

// Problem constants
#define NIMG 8
#define HDIM 128
#define WDIM 128
#define GNUM 64
#define DDIM 64
#define EDIM 32
#define UNK_CLASS 80
#define NBLK 4096                 // AE streaming blocks (exact 8-float4 cover)
#define DBLK 512                  // density blocks (dispatched FIRST)
#define TOTBLK (NBLK + DBLK)
#define AE_THREADS (NBLK*256)     // 1048576 streaming threads

typedef float floatv4 __attribute__((ext_vector_type(4)));  // native vec for nontemporal

// R6: EXACTLY the R1 structure (best measured: 212.09us) with ONE change:
// the 8 AE loads are __builtin_nontemporal_load (no L2 allocate on a
// single-touch 134MB stream). R3 bundled nt-loads with a per-block
// __threadfence that collapsed BW; this isolates the nt variable.
// R3's FETCH_SIZE=64MB showed nt loads still get L3 hits, so the only
// question is whether skipping L2 allocation lifts the ~2.5TB/s read cap.
__global__ __launch_bounds__(256) void fused_kernel(
    const float* __restrict__ err,        // [N,256,128,128]
    const float* __restrict__ err_map,    // [N,1,128,128]
    const float* __restrict__ gt_boxes,   // [N,64,4]
    const float* __restrict__ w1,         // [1,64]
    const float* __restrict__ b1,         // [64]
    const float* __restrict__ w2,         // [64,32] row-major, row d contiguous
    const float* __restrict__ b2,         // [32]
    const float* __restrict__ w3,         // [32,1]
    const float* __restrict__ b3,         // [1]
    const int*   __restrict__ gt_classes, // [N,64]
    float* __restrict__ ws)               // [DBLK] density partials + [NBLK] AE partials
{
    const int t = threadIdx.x;
    const int b = blockIdx.x;

    __shared__ float4 sboxes[GNUM];
    __shared__ int    scls[GNUM];
    __shared__ float  sw1[DDIM], sb1[DDIM], sb2[EDIM], sw3[EDIM];
    __shared__ __align__(16) float sw2[DDIM*EDIM];
    __shared__ float red[4];

    float part;                            // this block's partial (AE or density)

    if (b >= DBLK) {
        // -------- AE sum-of-squares: 8 nontemporal float4 in flight ----------
        const floatv4* __restrict__ e4 = (const floatv4*)err;
        const int gtid = ((b - DBLK) << 8) | t;       // [0, 1048576)
        floatv4 v0 = __builtin_nontemporal_load(e4 + gtid + 0*AE_THREADS);
        floatv4 v1 = __builtin_nontemporal_load(e4 + gtid + 1*AE_THREADS);
        floatv4 v2 = __builtin_nontemporal_load(e4 + gtid + 2*AE_THREADS);
        floatv4 v3 = __builtin_nontemporal_load(e4 + gtid + 3*AE_THREADS);
        floatv4 v4 = __builtin_nontemporal_load(e4 + gtid + 4*AE_THREADS);
        floatv4 v5 = __builtin_nontemporal_load(e4 + gtid + 5*AE_THREADS);
        floatv4 v6 = __builtin_nontemporal_load(e4 + gtid + 6*AE_THREADS);
        floatv4 v7 = __builtin_nontemporal_load(e4 + gtid + 7*AE_THREADS);
        float s0, s1, s2, s3;
        s0 = v0.x*v0.x; s1 = v0.y*v0.y; s2 = v0.z*v0.z; s3 = v0.w*v0.w;
        s0 = fmaf(v1.x,v1.x,s0); s1 = fmaf(v1.y,v1.y,s1); s2 = fmaf(v1.z,v1.z,s2); s3 = fmaf(v1.w,v1.w,s3);
        s0 = fmaf(v2.x,v2.x,s0); s1 = fmaf(v2.y,v2.y,s1); s2 = fmaf(v2.z,v2.z,s2); s3 = fmaf(v2.w,v2.w,s3);
        s0 = fmaf(v3.x,v3.x,s0); s1 = fmaf(v3.y,v3.y,s1); s2 = fmaf(v3.z,v3.z,s2); s3 = fmaf(v3.w,v3.w,s3);
        s0 = fmaf(v4.x,v4.x,s0); s1 = fmaf(v4.y,v4.y,s1); s2 = fmaf(v4.z,v4.z,s2); s3 = fmaf(v4.w,v4.w,s3);
        s0 = fmaf(v5.x,v5.x,s0); s1 = fmaf(v5.y,v5.y,s1); s2 = fmaf(v5.z,v5.z,s2); s3 = fmaf(v5.w,v5.w,s3);
        s0 = fmaf(v6.x,v6.x,s0); s1 = fmaf(v6.y,v6.y,s1); s2 = fmaf(v6.z,v6.z,s2); s3 = fmaf(v6.w,v6.w,s3);
        s0 = fmaf(v7.x,v7.x,s0); s1 = fmaf(v7.y,v7.y,s1); s2 = fmaf(v7.z,v7.z,s2); s3 = fmaf(v7.w,v7.w,s3);
        part = (s0+s1) + (s2+s3);
    } else {
        // ---------------- density + anchor matching (pure VALU path) ----------
        const int n  = b >> 6;                 // image
        const int m  = ((b & 63) << 8) | t;    // pixel in [0,16384)

        if (t < GNUM)               sboxes[t]      = ((const float4*)gt_boxes)[n*GNUM + t];
        else if (t < 2*GNUM)        scls[t-GNUM]   = gt_classes[n*GNUM + (t-GNUM)];
        else if (t < 2*GNUM+DDIM) { sw1[t-128] = w1[t-128]; sb1[t-128] = b1[t-128]; }
        else if (t < 2*GNUM+DDIM+EDIM) { sb2[t-192] = b2[t-192]; sw3[t-192] = w3[t-192]; }
        for (int i = t; i < DDIM*EDIM; i += 256)
            sw2[i] = w2[i];                               // no transpose needed
        __syncthreads();

        // ---- anchors at this pixel (A=3 aspect ratios, detectron2 order) ----
        const float cx = (float)(m & (WDIM-1)) * 8.0f;
        const float cy = (float)(m >> 7) * 8.0f;
        const float s05 = sqrtf(0.5f), s2r = sqrtf(2.0f);
        const float hw0 = 0.5f*(32.0f/s05), hh0 = 0.5f*(32.0f*s05);
        const float hw1 = 16.0f,            hh1 = 16.0f;
        const float hw2 = 0.5f*(32.0f/s2r), hh2 = 0.5f*(32.0f*s2r);

        const float ax1[3] = {cx-hw0, cx-hw1, cx-hw2};
        const float ay1[3] = {cy-hh0, cy-hh1, cy-hh2};
        const float ax2[3] = {cx+hw0, cx+hw1, cx+hw2};
        const float ay2[3] = {cy+hh0, cy+hh1, cy+hh2};
        float areaA[3];
        #pragma unroll
        for (int a = 0; a < 3; ++a) areaA[a] = (ax2[a]-ax1[a])*(ay2[a]-ay1[a]);

        // per-anchor best GT (division-free argmax: iou = inter/dn, dn > 0)
        float bi[3] = {-1.f,-1.f,-1.f}, bd[3] = {1.f,1.f,1.f};
        int   idx[3] = {0,0,0};

        for (int g = 0; g < GNUM; ++g) {
            const float4 bx = sboxes[g];                  // LDS broadcast
            const float areaB = (bx.z-bx.x)*(bx.w-bx.y);
            #pragma unroll
            for (int a = 0; a < 3; ++a) {
                float lx = fmaxf(bx.x, ax1[a]), ly = fmaxf(bx.y, ay1[a]);
                float rx = fminf(bx.z, ax2[a]), ry = fminf(bx.w, ay2[a]);
                float iw = fmaxf(rx-lx, 0.f),   ih = fmaxf(ry-ly, 0.f);
                float inter = iw*ih;
                float dn = fmaxf(areaB + areaA[a] - inter, 1e-9f);
                // strict > keeps FIRST max, matching jnp.argmax
                if (inter*bd[a] > bi[a]*dn) { bi[a]=inter; bd[a]=dn; idx[a]=g; }
            }
        }
        const bool unk = (scls[idx[0]] == UNK_CLASS) |
                         (scls[idx[1]] == UNK_CLASS) |
                         (scls[idx[2]] == UNK_CLASS);
        const float mask = unk ? 1.0f : 0.0f;

        // ---- density MLP, loop-swapped: acc[32] over layer-2 outputs ----
        const float xv = err_map[(n << 14) + m];
        float acc[EDIM];
        #pragma unroll
        for (int e = 0; e < EDIM; ++e) acc[e] = sb2[e];

        const float4* __restrict__ sw2v = (const float4*)sw2;
        for (int d = 0; d < DDIM; ++d) {
            const float h = fmaxf(fmaf(xv, sw1[d], sb1[d]), 0.0f);
            #pragma unroll
            for (int j = 0; j < 8; ++j) {
                float4 wv = sw2v[(d << 3) + j];           // LDS broadcast (row d of w2)
                acc[4*j+0] = fmaf(h, wv.x, acc[4*j+0]);
                acc[4*j+1] = fmaf(h, wv.y, acc[4*j+1]);
                acc[4*j+2] = fmaf(h, wv.z, acc[4*j+2]);
                acc[4*j+3] = fmaf(h, wv.w, acc[4*j+3]);
            }
        }
        float p = b3[0];
        #pragma unroll
        for (int e = 0; e < EDIM; ++e)
            p = fmaf(fmaxf(acc[e], 0.0f), sw3[e], p);

        // stable BCE-with-logits term: logaddexp(0,p) - p*mask
        part = fmaxf(p, 0.0f) + log1pf(expf(-fabsf(p))) - p*mask;
    }

    // ---- block reduction ----
    float x = part;
    #pragma unroll
    for (int off = 32; off > 0; off >>= 1)
        x += __shfl_xor(x, off, 64);
    if ((t & 63) == 0) red[t >> 6] = x;
    __syncthreads();
    if (t == 0)
        ws[b] = (red[0]+red[1]) + (red[2]+red[3]);
}

__global__ __launch_bounds__(256) void finalize_kernel(const float* __restrict__ ws,
                                                       float* __restrict__ out)
{
    const int t = threadIdx.x;
    float sa = 0.f, sd = 0.f;
    for (int i = t; i < NBLK; i += 256) sa += ws[DBLK + i];
    for (int i = t; i < DBLK; i += 256) sd += ws[i];
    #pragma unroll
    for (int off = 32; off > 0; off >>= 1) {
        sa += __shfl_xor(sa, off, 64);
        sd += __shfl_xor(sd, off, 64);
    }
    __shared__ float ra[4], rd[4];
    if ((t & 63) == 0) { ra[t >> 6] = sa; rd[t >> 6] = sd; }
    __syncthreads();
    if (t == 0) {
        out[0] = ((ra[0]+ra[1])+(ra[2]+ra[3])) * (1.0f/33554432.0f); // loss_ae
        out[1] = ((rd[0]+rd[1])+(rd[2]+rd[3])) * (1.0f/131072.0f);   // loss_density
    }
}

extern "C" void kernel_launch(void* const* d_in, const int* in_sizes, int n_in,
                              void* d_out, int out_size, void* d_ws, size_t ws_size,
                              hipStream_t stream) {
    const float* err        = (const float*)d_in[0];
    const float* err_map    = (const float*)d_in[1];
    const float* gt_boxes   = (const float*)d_in[2];
    const float* w1         = (const float*)d_in[3];
    const float* b1         = (const float*)d_in[4];
    const float* w2         = (const float*)d_in[5];
    const float* b2         = (const float*)d_in[6];
    const float* w3         = (const float*)d_in[7];
    const float* b3         = (const float*)d_in[8];
    const int*   gt_classes = (const int*)d_in[9];
    float* out = (float*)d_out;
    float* ws  = (float*)d_ws;

    fused_kernel<<<TOTBLK, 256, 0, stream>>>(err, err_map, gt_boxes, w1, b1, w2, b2,
                                             w3, b3, gt_classes, ws);
    finalize_kernel<<<1, 256, 0, stream>>>(ws, out);
}